// Round 4
// baseline (279.457 us; speedup 1.0000x reference)
//
#include <hip/hip_runtime.h>
#include <hip/hip_bf16.h>
#include <stdint.h>

typedef unsigned short u16;
typedef short s16x8 __attribute__((ext_vector_type(8)));
typedef float f32x4 __attribute__((ext_vector_type(4)));
typedef uint32_t u32x4 __attribute__((ext_vector_type(4)));

__device__ __forceinline__ uint32_t pack_bf16(float lo, float hi) {
  float2 f; f.x = lo; f.y = hi;
  __hip_bfloat162 h = __float22bfloat162_rn(f);
  union { __hip_bfloat162 h; uint32_t u; } c; c.h = h;
  return c.u;
}
__device__ __forceinline__ u16 f2bf(float f) {
  union { float f; uint32_t u; } a; a.f = f;
  uint32_t u = a.u;
  return (u16)((u + 0x7fffu + ((u >> 16) & 1u)) >> 16);
}
__device__ __forceinline__ float bf2f(uint32_t hbits) {
  union { uint32_t u; float f; } a; a.u = hbits << 16;
  return a.f;
}

// ---------------------------------------------------------------- fused prep
__global__ __launch_bounds__(256) void prep_all(
    const float* __restrict__ L1, const float* __restrict__ L2,
    const float* __restrict__ L3, const float* __restrict__ L4,
    const float* __restrict__ ws_w, const float* __restrict__ wp_w,
    u16* __restrict__ T1, u16* __restrict__ T2,
    u16* __restrict__ T3, u16* __restrict__ T4,
    u16* __restrict__ dWs, u16* __restrict__ dWp) {
  const int bid = blockIdx.x;
  const int t = threadIdx.x;

  if (bid >= 2720) {  // ---- W convert: 159744 f32 total as 39936 float4s
    int t0 = (bid - 2720) * 256 + t;
    for (int i = t0; i < 39936; i += 8192) {
      const float* s; u16* d; int off;
      if (i < 38400) { s = ws_w; d = dWs; off = 4 * i; }
      else           { s = wp_w; d = dWp; off = 4 * (i - 38400); }
      f32x4 v = *(const f32x4*)(s + off);
      uint2 o;
      o.x = pack_bf16(v.x, v.y);
      o.y = pack_bf16(v.z, v.w);
      *(uint2*)(d + off) = o;
    }
    return;
  }

  const float* src; u16* dst; int HW, tiles, rel;
  if (bid < 2048)      { src = L1; dst = T1; HW = 16384; tiles = 256; rel = bid; }
  else if (bid < 2560) { src = L2; dst = T2; HW = 4096;  tiles = 64;  rel = bid - 2048; }
  else if (bid < 2688) { src = L3; dst = T3; HW = 1024;  tiles = 16;  rel = bid - 2560; }
  else                 { src = L4; dst = T4; HW = 256;   tiles = 4;   rel = bid - 2688; }
  const int b = rel / tiles, hw0 = (rel % tiles) * 64;

  __shared__ uint32_t tileD[96 * 65];   // [c2][hw], stride 65 -> <=2-way banks
  const float* sb = src + (size_t)b * 192 * HW + hw0;
  for (int i = 0; i < 6; ++i) {
    int idx = i * 256 + t;                 // 1536 = 96 c2 x 16 hw4
    int c2 = idx >> 4, hw4 = idx & 15;
    f32x4 a = *(const f32x4*)(sb + (size_t)(2 * c2) * HW + hw4 * 4);
    f32x4 c = *(const f32x4*)(sb + (size_t)(2 * c2 + 1) * HW + hw4 * 4);
    uint32_t* w = &tileD[c2 * 65 + hw4 * 4];
    w[0] = pack_bf16(a.x, c.x);
    w[1] = pack_bf16(a.y, c.y);
    w[2] = pack_bf16(a.z, c.z);
    w[3] = pack_bf16(a.w, c.w);
  }
  __syncthreads();
  uint32_t* d = (uint32_t*)(dst + ((size_t)b * HW + hw0) * 192);
  for (int i = 0; i < 12; ++i) {
    int e = i * 256 + t;                   // 3072 = 64 hw x 48 cp
    int hw = e / 48, cp = e - hw * 48;
    uint2 v;
    v.x = tileD[(cp * 2) * 65 + hw];
    v.y = tileD[(cp * 2 + 1) * 65 + hw];
    *(uint2*)(d + hw * 96 + cp * 2) = v;
  }
}

// ---------------------------------------------------------------- main fused
// 32 points/block, 1024 blocks, 256 threads (4 waves). Each wave: 2 M-tiles x
// 3 N-tiles, 3-deep software-pipelined K-loop. LN in-register via shfl.
__global__ __launch_bounds__(256, 3) void seed_main(
    const float* __restrict__ coords,
    const u16* __restrict__ T1, const u16* __restrict__ T2,
    const u16* __restrict__ T3, const u16* __restrict__ T4,
    const u16* __restrict__ Wseed, const u16* __restrict__ Wpos,
    const float* __restrict__ seed_b, const float* __restrict__ ln_g,
    const float* __restrict__ ln_b, const float* __restrict__ pos_b,
    float* __restrict__ out_seed, float* __restrict__ out_pos,
    float* __restrict__ out_cg) {

  __shared__ __align__(16) u16 xt[32 * 808];   // 51.7 KB
  __shared__ float part_s[32][4], part_q[32][4];

  const int t = threadIdx.x;
  const int gp0 = blockIdx.x * 32;
  const int b = gp0 >> 12;

  // ---- center grid out
  if (t < 64) {
    int p = t >> 1, xy = t & 1;
    float c = coords[(gp0 + p) * 2 + xy];
    out_cg[(gp0 + p) * 2 + xy] = c * (2.0f / 511.0f) - 1.0f;
  }
  // ---- PE: 32 pts x 32 vals -> xt cols 768..799
  for (int i = 0; i < 4; ++i) {
    int e = i * 256 + t;
    int p = e >> 5, j = e & 31;
    float c = coords[(gp0 + p) * 2 + ((j >> 4) & 1)] * (1.0f / 512.0f);
    float v = c * (float)(1 << (j & 7));
    float a = (v - floorf(v)) * 6.283185307179586f;
    float r = (j & 8) ? __cosf(a) : __sinf(a);
    xt[p * 808 + 768 + j] = f2bf(r);
  }

  // ---- gather: thread owns one (p,lv); streams 12 contiguous 16B chunks
  {
    const u16* B1 = T1 + (size_t)b * 16384 * 192;
    const u16* B2 = T2 + (size_t)b * 4096 * 192;
    const u16* B3 = T3 + (size_t)b * 1024 * 192;
    const u16* B4 = T4 + (size_t)b * 256 * 192;
    int plv = t >> 1;                  // [0,128)
    int lv = plv & 3, p = plv >> 2;
    int half = t & 1;                  // lane pair covers full 384B row
    float cx = coords[(gp0 + p) * 2 + 0];
    float cy = coords[(gp0 + p) * 2 + 1];
    float gx = cx * (2.0f / 511.0f) - 1.0f;
    float gy = cy * (2.0f / 511.0f) - 1.0f;
    int Wl = 128 >> lv;
    float ix = (gx + 1.0f) * 0.5f * (float)(Wl - 1);
    float iy = (gy + 1.0f) * 0.5f * (float)(Wl - 1);
    float fx = floorf(ix), fy = floorf(iy);
    float wx = ix - fx, wy = iy - fy;
    int x0 = (int)fx, y0 = (int)fy;
    int x1 = min(max(x0 + 1, 0), Wl - 1), y1 = min(max(y0 + 1, 0), Wl - 1);
    x0 = min(max(x0, 0), Wl - 1); y0 = min(max(y0, 0), Wl - 1);
    const u16* base = (lv == 0) ? B1 : (lv == 1) ? B2 : (lv == 2) ? B3 : B4;
    const u16* b00 = base + (y0 * Wl + x0) * 192 + half * 96;
    const u16* b01 = base + (y0 * Wl + x1) * 192 + half * 96;
    const u16* b10 = base + (y1 * Wl + x0) * 192 + half * 96;
    const u16* b11 = base + (y1 * Wl + x1) * 192 + half * 96;
    float w00 = (1.0f - wx) * (1.0f - wy), w01 = wx * (1.0f - wy);
    float w10 = (1.0f - wx) * wy,          w11 = wx * wy;
    u16* dstp = xt + p * 808 + lv * 192 + half * 96;
#pragma unroll
    for (int ii = 0; ii < 6; ++ii) {     // 2 chunks per step -> 8 loads in flight
      int ca = ii * 16, cb = ii * 16 + 8;
      u32x4 qa00 = *(const u32x4*)(b00 + ca), qb00 = *(const u32x4*)(b00 + cb);
      u32x4 qa01 = *(const u32x4*)(b01 + ca), qb01 = *(const u32x4*)(b01 + cb);
      u32x4 qa10 = *(const u32x4*)(b10 + ca), qb10 = *(const u32x4*)(b10 + cb);
      u32x4 qa11 = *(const u32x4*)(b11 + ca), qb11 = *(const u32x4*)(b11 + cb);
      u32x4 oa, ob;
#pragma unroll
      for (int k = 0; k < 4; ++k) {
        float lo = bf2f(qa00[k] & 0xffff) * w00 + bf2f(qa01[k] & 0xffff) * w01 +
                   bf2f(qa10[k] & 0xffff) * w10 + bf2f(qa11[k] & 0xffff) * w11;
        float hi = bf2f(qa00[k] >> 16) * w00 + bf2f(qa01[k] >> 16) * w01 +
                   bf2f(qa10[k] >> 16) * w10 + bf2f(qa11[k] >> 16) * w11;
        oa[k] = pack_bf16(lo, hi);
        lo = bf2f(qb00[k] & 0xffff) * w00 + bf2f(qb01[k] & 0xffff) * w01 +
             bf2f(qb10[k] & 0xffff) * w10 + bf2f(qb11[k] & 0xffff) * w11;
        hi = bf2f(qb00[k] >> 16) * w00 + bf2f(qb01[k] >> 16) * w01 +
             bf2f(qb10[k] >> 16) * w10 + bf2f(qb11[k] >> 16) * w11;
        ob[k] = pack_bf16(lo, hi);
      }
      *(u32x4*)(dstp + ca) = oa;
      *(u32x4*)(dstp + cb) = ob;
    }
  }
  __syncthreads();

  // ---- MFMA: wave -> 2 M-tiles x 3 N-tiles, 3-deep pipelined K-loop
  const int lid = t & 63, wv = t >> 6;
  const int quad = lid >> 4, mrow = lid & 15;
  const int nt0 = wv * 3;

  const u16* arow0 = xt + mrow * 808 + quad * 8;
  const u16* arow1 = arow0 + 16 * 808;
  const u16* w0 = Wseed + (size_t)((nt0 + 0) * 16 + mrow) * 800 + quad * 8;
  const u16* w1 = w0 + 16 * 800;
  const u16* w2 = w1 + 16 * 800;

  f32x4 accS[2][3];
#pragma unroll
  for (int mt = 0; mt < 2; ++mt)
#pragma unroll
    for (int j = 0; j < 3; ++j) accS[mt][j] = (f32x4)0.0f;

  s16x8 abuf[3][2], bbuf[3][3];
#pragma unroll
  for (int s = 0; s < 3; ++s) {
    int ko = s * 32;
    abuf[s][0] = *(const s16x8*)(arow0 + ko);
    abuf[s][1] = *(const s16x8*)(arow1 + ko);
    bbuf[s][0] = *(const s16x8*)(w0 + ko);
    bbuf[s][1] = *(const s16x8*)(w1 + ko);
    bbuf[s][2] = *(const s16x8*)(w2 + ko);
  }
#pragma unroll
  for (int kc = 0; kc < 25; ++kc) {
    const int cur = kc % 3;
    s16x8 a0 = abuf[cur][0], a1 = abuf[cur][1];
    s16x8 b0 = bbuf[cur][0], b1 = bbuf[cur][1], b2 = bbuf[cur][2];
    int nk = kc + 3;
    if (nk < 25) {
      int ko = nk * 32;
      abuf[cur][0] = *(const s16x8*)(arow0 + ko);
      abuf[cur][1] = *(const s16x8*)(arow1 + ko);
      bbuf[cur][0] = *(const s16x8*)(w0 + ko);
      bbuf[cur][1] = *(const s16x8*)(w1 + ko);
      bbuf[cur][2] = *(const s16x8*)(w2 + ko);
    }
    accS[0][0] = __builtin_amdgcn_mfma_f32_16x16x32_bf16(a0, b0, accS[0][0], 0, 0, 0);
    accS[1][0] = __builtin_amdgcn_mfma_f32_16x16x32_bf16(a1, b0, accS[1][0], 0, 0, 0);
    accS[0][1] = __builtin_amdgcn_mfma_f32_16x16x32_bf16(a0, b1, accS[0][1], 0, 0, 0);
    accS[1][1] = __builtin_amdgcn_mfma_f32_16x16x32_bf16(a1, b1, accS[1][1], 0, 0, 0);
    accS[0][2] = __builtin_amdgcn_mfma_f32_16x16x32_bf16(a0, b2, accS[0][2], 0, 0, 0);
    accS[1][2] = __builtin_amdgcn_mfma_f32_16x16x32_bf16(a1, b2, accS[1][2], 0, 0, 0);
  }

  // ---- pos: K=32 (PE chunk), A re-read from LDS
  {
    s16x8 ap0 = *(const s16x8*)(arow0 + 768);
    s16x8 ap1 = *(const s16x8*)(arow1 + 768);
#pragma unroll
    for (int j = 0; j < 3; ++j) {
      int n = (nt0 + j) * 16 + mrow;
      s16x8 bw = *(const s16x8*)(Wpos + n * 32 + quad * 8);
      f32x4 p0 = (f32x4)0.0f, p1 = (f32x4)0.0f;
      p0 = __builtin_amdgcn_mfma_f32_16x16x32_bf16(ap0, bw, p0, 0, 0, 0);
      p1 = __builtin_amdgcn_mfma_f32_16x16x32_bf16(ap1, bw, p1, 0, 0, 0);
      float pb = pos_b[n];
#pragma unroll
      for (int r = 0; r < 4; ++r) {
        out_pos[(size_t)(gp0 + quad * 4 + r) * 192 + n] = p0[r] + pb;
        out_pos[(size_t)(gp0 + 16 + quad * 4 + r) * 192 + n] = p1[r] + pb;
      }
    }
  }

  // ---- bias add + LN partial stats (in-register, shfl within quad group)
#pragma unroll
  for (int j = 0; j < 3; ++j) {
    float sb = seed_b[(nt0 + j) * 16 + mrow];
#pragma unroll
    for (int mt = 0; mt < 2; ++mt)
#pragma unroll
      for (int r = 0; r < 4; ++r) accS[mt][j][r] += sb;
  }
#pragma unroll
  for (int mt = 0; mt < 2; ++mt)
#pragma unroll
    for (int r = 0; r < 4; ++r) {
      float s = accS[mt][0][r] + accS[mt][1][r] + accS[mt][2][r];
      float q = accS[mt][0][r] * accS[mt][0][r] + accS[mt][1][r] * accS[mt][1][r] +
                accS[mt][2][r] * accS[mt][2][r];
#pragma unroll
      for (int d = 1; d < 16; d <<= 1) {
        s += __shfl_xor(s, d, 16);
        q += __shfl_xor(q, d, 16);
      }
      if (mrow == 0) {
        int row = mt * 16 + quad * 4 + r;
        part_s[row][wv] = s;
        part_q[row][wv] = q;
      }
    }
  __syncthreads();

  // ---- finalize LN + write seed
#pragma unroll
  for (int mt = 0; mt < 2; ++mt) {
    float mu[4], rs[4];
#pragma unroll
    for (int r = 0; r < 4; ++r) {
      int row = mt * 16 + quad * 4 + r;
      float s = part_s[row][0] + part_s[row][1] + part_s[row][2] + part_s[row][3];
      float q = part_q[row][0] + part_q[row][1] + part_q[row][2] + part_q[row][3];
      float m = s * (1.0f / 192.0f);
      float var = q * (1.0f / 192.0f) - m * m;
      mu[r] = m;
      rs[r] = rsqrtf(var + 1e-5f);
    }
#pragma unroll
    for (int j = 0; j < 3; ++j) {
      int n = (nt0 + j) * 16 + mrow;
      float g = ln_g[n], bb = ln_b[n];
#pragma unroll
      for (int r = 0; r < 4; ++r) {
        int row = gp0 + mt * 16 + quad * 4 + r;
        out_seed[(size_t)row * 192 + n] = (accS[mt][j][r] - mu[r]) * rs[r] * g + bb;
      }
    }
  }
}

extern "C" void kernel_launch(void* const* d_in, const int* in_sizes, int n_in,
                              void* d_out, int out_size, void* d_ws, size_t ws_size,
                              hipStream_t stream) {
  const float* coords  = (const float*)d_in[0];
  const float* L1      = (const float*)d_in[1];
  const float* L2      = (const float*)d_in[2];
  const float* L3      = (const float*)d_in[3];
  const float* L4      = (const float*)d_in[4];
  const float* Wseed_w = (const float*)d_in[5];
  const float* Wseed_b = (const float*)d_in[6];
  const float* ln_g    = (const float*)d_in[7];
  const float* ln_b    = (const float*)d_in[8];
  const float* Wpos_w  = (const float*)d_in[9];
  const float* Wpos_b  = (const float*)d_in[10];

  u16* T1  = (u16*)d_ws;
  u16* T2  = T1 + (size_t)8 * 16384 * 192;
  u16* T3  = T2 + (size_t)8 * 4096 * 192;
  u16* T4  = T3 + (size_t)8 * 1024 * 192;
  u16* Wsd = T4 + (size_t)8 * 256 * 192;
  u16* Wps = Wsd + 153600;

  prep_all<<<2752, 256, 0, stream>>>(L1, L2, L3, L4, Wseed_w, Wpos_w,
                                     T1, T2, T3, T4, Wsd, Wps);

  float* out_seed = (float*)d_out;
  float* out_pos  = out_seed + (size_t)32768 * 192;
  float* out_cg   = out_pos  + (size_t)32768 * 192;

  seed_main<<<1024, 256, 0, stream>>>(coords, T1, T2, T3, T4, Wsd, Wps,
                                      Wseed_b, ln_g, ln_b, Wpos_b,
                                      out_seed, out_pos, out_cg);
}